// Round 4
// baseline (291.279 us; speedup 1.0000x reference)
//
#include <hip/hip_runtime.h>

// PointNetKnnInterpolator on MI355X (gfx950).
// h = [x[x_idx], pos_x[x_idx]-pos_y[y_idx]]  (400000 x 67)
// net = relu(h)@W0a+b0a ; dx = relu(net)@W1a+b1a ; h2 = h@Wsa + dx
// net2 = relu(h2)@W0b+b0b ; h3 = h2 + relu(net2)@W1b+b1b
// out[y] = max over 8 consecutive rows of h3.
//
// R4: LDS-pipe is the diagnosed limiter (48 KB of B-frag ds_read_b128 per
// 16-row tile ~= 61 KB LDS/tile; per-CU serialization ~25-29 us of the 54).
//   - M=32 per wave: two 16-row tiles share every B-fragment read -> LDS
//     traffic/tile 61 -> ~36 KB, plus 2x independent MFMA chains (ILP).
//   - dynamic pair assignment via atomicAdd counter in d_ws (removes the
//     static-schedule tail imbalance across CUs).
// Block=512 (8 waves) shares one 48 KB bfrag copy; LDS 66 KB -> 2 blocks/CU
// = 16 waves/CU. One trans buffer per wave, reused sequentially per tile.

typedef _Float16 f16x8 __attribute__((ext_vector_type(8)));
typedef float    f32x4 __attribute__((ext_vector_type(4)));

constexpr int NROWS   = 50000 * 8;   // NY * K
constexpr int NPAIRS  = NROWS / 32;  // 12500 (32 rows per wave-iteration)
constexpr int NFRAG   = 48;          // 12 W0a + 8 W1a + 12 Wsa + 8 W0b + 8 W1b
constexpr int TSTRIDE = 72;          // halves per row of transition buffer
constexpr int BW      = 8;           // waves per block (block = 512)

static __device__ __forceinline__ f16x8 relu8(f16x8 v) {
    f16x8 r;
#pragma unroll
    for (int j = 0; j < 8; ++j) {
        _Float16 x = v[j];
        r[j] = x > (_Float16)0 ? x : (_Float16)0;
    }
    return r;
}

// write relu(acc[4]) in C-layout to tbuf, read back two A-fragments.
// Leading fence also orders any previous reads of tbuf before overwrite.
static __device__ __forceinline__ void xpose_relu(const f32x4* acc, _Float16* tbuf,
                                                  int q, int n0, f16x8* af) {
    __threadfence_block();
#pragma unroll
    for (int t = 0; t < 4; ++t)
#pragma unroll
        for (int r = 0; r < 4; ++r) {
            float v = acc[t][r];
            tbuf[(q * 4 + r) * TSTRIDE + t * 16 + n0] = (_Float16)(v > 0.0f ? v : 0.0f);
        }
    __threadfence_block();
#pragma unroll
    for (int s = 0; s < 2; ++s)
        af[s] = *(const f16x8*)&tbuf[n0 * TSTRIDE + s * 32 + q * 8];
}

__global__ __launch_bounds__(512, 4)
void pointnet_fused(const float* __restrict__ x,
                    const float* __restrict__ pos_x,
                    const float* __restrict__ pos_y,
                    const int*   __restrict__ x_idx,
                    const float* __restrict__ W0a, const float* __restrict__ b0a,
                    const float* __restrict__ W1a, const float* __restrict__ b1a,
                    const float* __restrict__ Wsa,
                    const float* __restrict__ W0b, const float* __restrict__ b0b,
                    const float* __restrict__ W1b, const float* __restrict__ b1b,
                    float* __restrict__ out,
                    int* __restrict__ ctr)
{
    __shared__ __align__(16) _Float16 bfrag[NFRAG * 64 * 8];       // 48 KiB
    __shared__ __align__(16) _Float16 trans[BW][16 * TSTRIDE];     // 18 KiB

    const int tid = threadIdx.x;

    // ---- expand weights into B-fragment order (once per block) ----
    for (int p = tid; p < NFRAG * 64; p += 512) {
        const int f = p >> 6;
        const int l = p & 63;
        const float* W; int krows, fl;
        if (f < 12)      { W = W0a; krows = 67; fl = f; }
        else if (f < 20) { W = W1a; krows = 64; fl = f - 12; }
        else if (f < 32) { W = Wsa; krows = 67; fl = f - 20; }
        else if (f < 40) { W = W0b; krows = 64; fl = f - 32; }
        else             { W = W1b; krows = 64; fl = f - 40; }
        const int s = fl >> 2, t = fl & 3;
        const int n = t * 16 + (l & 15);
        const int kbase = s * 32 + (l >> 4) * 8;
        f16x8 v;
#pragma unroll
        for (int j = 0; j < 8; ++j) {
            const int k = kbase + j;
            v[j] = (_Float16)((k < krows) ? W[k * 64 + n] : 0.0f);
        }
        *(f16x8*)&bfrag[p * 8] = v;
    }
    __syncthreads();

    const int lane = tid & 63;
    const int wv   = tid >> 6;
    const int n0   = lane & 15;   // C col / A row m
    const int q    = lane >> 4;   // quad

    float bias0a[4], bias1a[4], bias0b[4], bias1b[4];
#pragma unroll
    for (int t = 0; t < 4; ++t) {
        bias0a[t] = b0a[t * 16 + n0];
        bias1a[t] = b1a[t * 16 + n0];
        bias0b[t] = b0b[t * 16 + n0];
        bias1b[t] = b1b[t * 16 + n0];
    }

    _Float16* tbuf = trans[wv];

    for (;;) {
        // ---- dynamic pair assignment (one atomic per wave-iteration) ----
        int pr = 0;
        if (lane == 0) pr = atomicAdd(ctr, 1);
        pr = __shfl(pr, 0, 64);
        if (pr >= NPAIRS) break;

        // ---- gather A-side: h for both 16-row tiles (K padded 67->96) ----
        f16x8 hn[2][3];
#pragma unroll
        for (int u = 0; u < 2; ++u) {
            const int row = pr * 32 + u * 16 + n0;
            const int xi  = x_idx[row];
            const float* xp = x + (long)xi * 64;
#pragma unroll
            for (int s = 0; s < 2; ++s) {
                const float4* src = (const float4*)(xp + s * 32 + q * 8);
                float4 v0 = src[0], v1 = src[1];
                float vals[8] = {v0.x, v0.y, v0.z, v0.w, v1.x, v1.y, v1.z, v1.w};
#pragma unroll
                for (int j = 0; j < 8; ++j)
                    hn[u][s][j] = (_Float16)vals[j];
            }
            f16x8 z = {};
            hn[u][2] = z;
            if (q == 0) {
                const int yi = row >> 3;
#pragma unroll
                for (int j = 0; j < 3; ++j)
                    hn[u][2][j] = (_Float16)(pos_x[xi * 3 + j] - pos_y[yi * 3 + j]);
            }
        }

        // ---- mm1: net = relu(h) @ W0a + b0a  (B-frag shared by both tiles) ----
        f16x8 hr[2][3];
#pragma unroll
        for (int u = 0; u < 2; ++u)
#pragma unroll
            for (int s = 0; s < 3; ++s)
                hr[u][s] = relu8(hn[u][s]);

        f32x4 A1[2][4];
#pragma unroll
        for (int u = 0; u < 2; ++u)
#pragma unroll
            for (int t = 0; t < 4; ++t)
                A1[u][t] = (f32x4){bias0a[t], bias0a[t], bias0a[t], bias0a[t]};
#pragma unroll
        for (int s = 0; s < 3; ++s)
#pragma unroll
            for (int t = 0; t < 4; ++t) {
                f16x8 b = *(const f16x8*)&bfrag[((s * 4 + t) * 64 + lane) * 8];
                A1[0][t] = __builtin_amdgcn_mfma_f32_16x16x32_f16(hr[0][s], b, A1[0][t], 0, 0, 0);
                A1[1][t] = __builtin_amdgcn_mfma_f32_16x16x32_f16(hr[1][s], b, A1[1][t], 0, 0, 0);
            }

        // ---- relu(net) -> A-frags (sequential per tile through one buffer) ----
        f16x8 a2[2][2];
        xpose_relu(A1[0], tbuf, q, n0, a2[0]);
        xpose_relu(A1[1], tbuf, q, n0, a2[1]);

        // ---- mm2+mm3: h2 = relu(net)@W1a + b1a + h@Wsa ----
        f32x4 A2[2][4];
#pragma unroll
        for (int u = 0; u < 2; ++u)
#pragma unroll
            for (int t = 0; t < 4; ++t)
                A2[u][t] = (f32x4){bias1a[t], bias1a[t], bias1a[t], bias1a[t]};
#pragma unroll
        for (int s = 0; s < 2; ++s)
#pragma unroll
            for (int t = 0; t < 4; ++t) {
                f16x8 b = *(const f16x8*)&bfrag[((12 + s * 4 + t) * 64 + lane) * 8];
                A2[0][t] = __builtin_amdgcn_mfma_f32_16x16x32_f16(a2[0][s], b, A2[0][t], 0, 0, 0);
                A2[1][t] = __builtin_amdgcn_mfma_f32_16x16x32_f16(a2[1][s], b, A2[1][t], 0, 0, 0);
            }
#pragma unroll
        for (int s = 0; s < 3; ++s)
#pragma unroll
            for (int t = 0; t < 4; ++t) {
                f16x8 b = *(const f16x8*)&bfrag[((20 + s * 4 + t) * 64 + lane) * 8];
                A2[0][t] = __builtin_amdgcn_mfma_f32_16x16x32_f16(hn[0][s], b, A2[0][t], 0, 0, 0);
                A2[1][t] = __builtin_amdgcn_mfma_f32_16x16x32_f16(hn[1][s], b, A2[1][t], 0, 0, 0);
            }

        // ---- relu(h2) -> A-frags (A2 keeps h2 for the residual) ----
        f16x8 a4[2][2];
        xpose_relu(A2[0], tbuf, q, n0, a4[0]);
        xpose_relu(A2[1], tbuf, q, n0, a4[1]);

        // ---- mm4: net2 = relu(h2)@W0b + b0b ----
        f32x4 A3[2][4];
#pragma unroll
        for (int u = 0; u < 2; ++u)
#pragma unroll
            for (int t = 0; t < 4; ++t)
                A3[u][t] = (f32x4){bias0b[t], bias0b[t], bias0b[t], bias0b[t]};
#pragma unroll
        for (int s = 0; s < 2; ++s)
#pragma unroll
            for (int t = 0; t < 4; ++t) {
                f16x8 b = *(const f16x8*)&bfrag[((32 + s * 4 + t) * 64 + lane) * 8];
                A3[0][t] = __builtin_amdgcn_mfma_f32_16x16x32_f16(a4[0][s], b, A3[0][t], 0, 0, 0);
                A3[1][t] = __builtin_amdgcn_mfma_f32_16x16x32_f16(a4[1][s], b, A3[1][t], 0, 0, 0);
            }

        // ---- relu(net2) -> A-frags ----
        f16x8 a5[2][2];
        xpose_relu(A3[0], tbuf, q, n0, a5[0]);
        xpose_relu(A3[1], tbuf, q, n0, a5[1]);

        // ---- mm5: h3 = h2 + relu(net2)@W1b + b1b ----
        f32x4 A4[2][4];
#pragma unroll
        for (int u = 0; u < 2; ++u)
#pragma unroll
            for (int t = 0; t < 4; ++t) {
                A4[u][t] = A2[u][t];
                A4[u][t][0] += bias1b[t]; A4[u][t][1] += bias1b[t];
                A4[u][t][2] += bias1b[t]; A4[u][t][3] += bias1b[t];
            }
#pragma unroll
        for (int s = 0; s < 2; ++s)
#pragma unroll
            for (int t = 0; t < 4; ++t) {
                f16x8 b = *(const f16x8*)&bfrag[((40 + s * 4 + t) * 64 + lane) * 8];
                A4[0][t] = __builtin_amdgcn_mfma_f32_16x16x32_f16(a5[0][s], b, A4[0][t], 0, 0, 0);
                A4[1][t] = __builtin_amdgcn_mfma_f32_16x16x32_f16(a5[1][s], b, A4[1][t], 0, 0, 0);
            }

        // ---- segment max over 8 rows & store (2 y per tile, 4 per pair) ----
#pragma unroll
        for (int u = 0; u < 2; ++u)
#pragma unroll
            for (int t = 0; t < 4; ++t) {
                float pm = fmaxf(fmaxf(A4[u][t][0], A4[u][t][1]),
                                 fmaxf(A4[u][t][2], A4[u][t][3]));
                pm = fmaxf(pm, __shfl_xor(pm, 16, 64));
                if ((q & 1) == 0) {
                    const int y = pr * 4 + u * 2 + (q >> 1);
                    out[(long)y * 64 + t * 16 + n0] = pm;
                }
            }
    }
}

extern "C" void kernel_launch(void* const* d_in, const int* in_sizes, int n_in,
                              void* d_out, int out_size, void* d_ws, size_t ws_size,
                              hipStream_t stream) {
    (void)in_sizes; (void)n_in; (void)ws_size; (void)out_size;
    hipMemsetAsync(d_ws, 0, 64, stream);   // zero the dynamic-work counter
    pointnet_fused<<<512, 512, 0, stream>>>(
        (const float*)d_in[0],   // x
        (const float*)d_in[1],   // pos_x
        (const float*)d_in[2],   // pos_y
        (const int*)  d_in[3],   // x_idx
        (const float*)d_in[5],  (const float*)d_in[6],   // W0a, b0a
        (const float*)d_in[7],  (const float*)d_in[8],   // W1a, b1a
        (const float*)d_in[9],                            // Wsa
        (const float*)d_in[10], (const float*)d_in[11],  // W0b, b0b
        (const float*)d_in[12], (const float*)d_in[13],  // W1b, b1b
        (float*)d_out,
        (int*)d_ws);
}

// Round 5
// 288.169 us; speedup vs baseline: 1.0108x; 1.0108x over previous
//
#include <hip/hip_runtime.h>

// PointNetKnnInterpolator on MI355X (gfx950).
// h = [x[x_idx], pos_x[x_idx]-pos_y[y_idx]]  (400000 x 67)
// net = relu(h)@W0a+b0a ; dx = relu(net)@W1a+b1a ; h2 = h@Wsa + dx
// net2 = relu(h2)@W0b+b0b ; h3 = h2 + relu(net2)@W1b+b1b
// out[y] = max over 8 consecutive rows of h3.
//
// R5: M=32 pairing (two 16-row tiles share every B-frag ds_read) WITHOUT the
// R4 register blowup (R4 spilled: FETCH 22->80MB, WRITE 14.5->45.8MB = scratch).
// Live-range fixes vs R4:
//   - mm3 (h@Wsa) runs FIRST on raw hn, then hn is relu'd IN PLACE for mm1
//     (kills hr[2][3], -24 VGPRs)
//   - mm5 accumulates into A2 in place (A2 holds h2 residual; kills A4, -32)
//   - biases live in LDS (1 KB), read per pair as broadcast ds_read_b32,
//     folded into the transpose as relu(acc+b)  (-16 always-live VGPRs)
// Widest point now ~A1(32)+A2(32)+hn(24)+addr ~= 110 < 128 cap of (512,4).
// Block=512 shares one 48 KB bfrag; LDS ~68 KB -> 2 blocks/CU = 16 waves/CU.

typedef _Float16 f16x8 __attribute__((ext_vector_type(8)));
typedef float    f32x4 __attribute__((ext_vector_type(4)));

constexpr int NROWS   = 50000 * 8;   // NY * K
constexpr int NPAIRS  = NROWS / 32;  // 12500 (32 rows per wave-iteration)
constexpr int NFRAG   = 48;          // 12 W0a + 8 W1a + 12 Wsa + 8 W0b + 8 W1b
constexpr int TSTRIDE = 72;          // halves per row of transition buffer
constexpr int BW      = 8;           // waves per block (block = 512)

// write relu(acc[4]+bias[4]) in C-layout to tbuf, read back two A-fragments.
// Leading fence orders any previous reads of tbuf before overwrite.
static __device__ __forceinline__ void xpose_relu(const f32x4* acc, const float* bb,
                                                  _Float16* tbuf, int q, int n0,
                                                  f16x8* af) {
    __threadfence_block();
#pragma unroll
    for (int t = 0; t < 4; ++t)
#pragma unroll
        for (int r = 0; r < 4; ++r) {
            float v = acc[t][r] + bb[t];
            tbuf[(q * 4 + r) * TSTRIDE + t * 16 + n0] = (_Float16)(v > 0.0f ? v : 0.0f);
        }
    __threadfence_block();
#pragma unroll
    for (int s = 0; s < 2; ++s)
        af[s] = *(const f16x8*)&tbuf[n0 * TSTRIDE + s * 32 + q * 8];
}

__global__ __launch_bounds__(512, 4)
void pointnet_fused(const float* __restrict__ x,
                    const float* __restrict__ pos_x,
                    const float* __restrict__ pos_y,
                    const int*   __restrict__ x_idx,
                    const float* __restrict__ W0a, const float* __restrict__ b0a,
                    const float* __restrict__ W1a, const float* __restrict__ b1a,
                    const float* __restrict__ Wsa,
                    const float* __restrict__ W0b, const float* __restrict__ b0b,
                    const float* __restrict__ W1b, const float* __restrict__ b1b,
                    float* __restrict__ out,
                    int* __restrict__ ctr)
{
    __shared__ __align__(16) _Float16 bfrag[NFRAG * 64 * 8];       // 48 KiB
    __shared__ __align__(16) _Float16 trans[BW][16 * TSTRIDE];     // 18 KiB
    __shared__ float bias_lds[4 * 64];                             // 1 KiB

    const int tid = threadIdx.x;

    // ---- expand weights into B-fragment order (once per block) ----
    for (int p = tid; p < NFRAG * 64; p += 512) {
        const int f = p >> 6;
        const int l = p & 63;
        const float* W; int krows, fl;
        if (f < 12)      { W = W0a; krows = 67; fl = f; }
        else if (f < 20) { W = W1a; krows = 64; fl = f - 12; }
        else if (f < 32) { W = Wsa; krows = 67; fl = f - 20; }
        else if (f < 40) { W = W0b; krows = 64; fl = f - 32; }
        else             { W = W1b; krows = 64; fl = f - 40; }
        const int s = fl >> 2, t = fl & 3;
        const int n = t * 16 + (l & 15);
        const int kbase = s * 32 + (l >> 4) * 8;
        f16x8 v;
#pragma unroll
        for (int j = 0; j < 8; ++j) {
            const int k = kbase + j;
            v[j] = (_Float16)((k < krows) ? W[k * 64 + n] : 0.0f);
        }
        *(f16x8*)&bfrag[p * 8] = v;
    }
    if (tid < 256) {
        const int L = tid >> 6, i = tid & 63;
        const float* b = (L == 0) ? b0a : (L == 1) ? b1a : (L == 2) ? b0b : b1b;
        bias_lds[tid] = b[i];
    }
    __syncthreads();

    const int lane = tid & 63;
    const int wv   = tid >> 6;
    const int n0   = lane & 15;   // C col / A row m
    const int q    = lane >> 4;   // quad

    _Float16* tbuf = trans[wv];

    for (;;) {
        // ---- dynamic pair assignment (one atomic per wave-iteration) ----
        int pr = 0;
        if (lane == 0) pr = atomicAdd(ctr, 1);
        pr = __shfl(pr, 0, 64);
        if (pr >= NPAIRS) break;

        // ---- gather A-side: h for both 16-row tiles (K padded 67->96) ----
        f16x8 hn[2][3];
#pragma unroll
        for (int u = 0; u < 2; ++u) {
            const int row = pr * 32 + u * 16 + n0;
            const int xi  = x_idx[row];
            const float* xp = x + (long)xi * 64;
#pragma unroll
            for (int s = 0; s < 2; ++s) {
                const float4* src = (const float4*)(xp + s * 32 + q * 8);
                float4 v0 = src[0], v1 = src[1];
                float vals[8] = {v0.x, v0.y, v0.z, v0.w, v1.x, v1.y, v1.z, v1.w};
#pragma unroll
                for (int j = 0; j < 8; ++j)
                    hn[u][s][j] = (_Float16)vals[j];
            }
            f16x8 z = {};
            hn[u][2] = z;
            if (q == 0) {
                const int yi = row >> 3;
#pragma unroll
                for (int j = 0; j < 3; ++j)
                    hn[u][2][j] = (_Float16)(pos_x[xi * 3 + j] - pos_y[yi * 3 + j]);
            }
        }

        // ---- mm3 FIRST: A2 = h @ Wsa  (raw hn; frags 20..31) ----
        f32x4 A2[2][4];
#pragma unroll
        for (int u = 0; u < 2; ++u)
#pragma unroll
            for (int t = 0; t < 4; ++t)
                A2[u][t] = (f32x4){0.f, 0.f, 0.f, 0.f};
#pragma unroll
        for (int s = 0; s < 3; ++s)
#pragma unroll
            for (int t = 0; t < 4; ++t) {
                f16x8 b = *(const f16x8*)&bfrag[((20 + s * 4 + t) * 64 + lane) * 8];
                A2[0][t] = __builtin_amdgcn_mfma_f32_16x16x32_f16(hn[0][s], b, A2[0][t], 0, 0, 0);
                A2[1][t] = __builtin_amdgcn_mfma_f32_16x16x32_f16(hn[1][s], b, A2[1][t], 0, 0, 0);
            }

        // ---- relu hn IN PLACE, then mm1: A1 = relu(h) @ W0a (frags 0..11) ----
#pragma unroll
        for (int u = 0; u < 2; ++u)
#pragma unroll
            for (int s = 0; s < 3; ++s)
#pragma unroll
                for (int j = 0; j < 8; ++j) {
                    _Float16 v = hn[u][s][j];
                    hn[u][s][j] = v > (_Float16)0 ? v : (_Float16)0;
                }

        f32x4 A1[2][4];
#pragma unroll
        for (int u = 0; u < 2; ++u)
#pragma unroll
            for (int t = 0; t < 4; ++t)
                A1[u][t] = (f32x4){0.f, 0.f, 0.f, 0.f};
#pragma unroll
        for (int s = 0; s < 3; ++s)
#pragma unroll
            for (int t = 0; t < 4; ++t) {
                f16x8 b = *(const f16x8*)&bfrag[((s * 4 + t) * 64 + lane) * 8];
                A1[0][t] = __builtin_amdgcn_mfma_f32_16x16x32_f16(hn[0][s], b, A1[0][t], 0, 0, 0);
                A1[1][t] = __builtin_amdgcn_mfma_f32_16x16x32_f16(hn[1][s], b, A1[1][t], 0, 0, 0);
            }

        // ---- transpose relu(A1 + b0a) -> a2 frags; mm2: A2 += a2 @ W1a ----
        float bb[4];
#pragma unroll
        for (int t = 0; t < 4; ++t) bb[t] = bias_lds[0 * 64 + t * 16 + n0];
        f16x8 a2[2][2];
        xpose_relu(A1[0], bb, tbuf, q, n0, a2[0]);
        xpose_relu(A1[1], bb, tbuf, q, n0, a2[1]);
#pragma unroll
        for (int s = 0; s < 2; ++s)
#pragma unroll
            for (int t = 0; t < 4; ++t) {
                f16x8 b = *(const f16x8*)&bfrag[((12 + s * 4 + t) * 64 + lane) * 8];
                A2[0][t] = __builtin_amdgcn_mfma_f32_16x16x32_f16(a2[0][s], b, A2[0][t], 0, 0, 0);
                A2[1][t] = __builtin_amdgcn_mfma_f32_16x16x32_f16(a2[1][s], b, A2[1][t], 0, 0, 0);
            }

        // ---- A2 += b1a (h2 complete); transpose relu(A2) -> a4 ----
#pragma unroll
        for (int t = 0; t < 4; ++t) bb[t] = bias_lds[1 * 64 + t * 16 + n0];
#pragma unroll
        for (int u = 0; u < 2; ++u)
#pragma unroll
            for (int t = 0; t < 4; ++t)
#pragma unroll
                for (int r = 0; r < 4; ++r)
                    A2[u][t][r] += bb[t];
        const float bz[4] = {0.f, 0.f, 0.f, 0.f};
        f16x8 a4[2][2];
        xpose_relu(A2[0], bz, tbuf, q, n0, a4[0]);
        xpose_relu(A2[1], bz, tbuf, q, n0, a4[1]);

        // ---- mm4: A3 = a4 @ W0b (frags 32..39) ----
        f32x4 A3[2][4];
#pragma unroll
        for (int u = 0; u < 2; ++u)
#pragma unroll
            for (int t = 0; t < 4; ++t)
                A3[u][t] = (f32x4){0.f, 0.f, 0.f, 0.f};
#pragma unroll
        for (int s = 0; s < 2; ++s)
#pragma unroll
            for (int t = 0; t < 4; ++t) {
                f16x8 b = *(const f16x8*)&bfrag[((32 + s * 4 + t) * 64 + lane) * 8];
                A3[0][t] = __builtin_amdgcn_mfma_f32_16x16x32_f16(a4[0][s], b, A3[0][t], 0, 0, 0);
                A3[1][t] = __builtin_amdgcn_mfma_f32_16x16x32_f16(a4[1][s], b, A3[1][t], 0, 0, 0);
            }

        // ---- transpose relu(A3 + b0b) -> a5; mm5: A2 += b1b + a5 @ W1b ----
#pragma unroll
        for (int t = 0; t < 4; ++t) bb[t] = bias_lds[2 * 64 + t * 16 + n0];
        f16x8 a5[2][2];
        xpose_relu(A3[0], bb, tbuf, q, n0, a5[0]);
        xpose_relu(A3[1], bb, tbuf, q, n0, a5[1]);

#pragma unroll
        for (int t = 0; t < 4; ++t) bb[t] = bias_lds[3 * 64 + t * 16 + n0];
#pragma unroll
        for (int u = 0; u < 2; ++u)
#pragma unroll
            for (int t = 0; t < 4; ++t)
#pragma unroll
                for (int r = 0; r < 4; ++r)
                    A2[u][t][r] += bb[t];
#pragma unroll
        for (int s = 0; s < 2; ++s)
#pragma unroll
            for (int t = 0; t < 4; ++t) {
                f16x8 b = *(const f16x8*)&bfrag[((40 + s * 4 + t) * 64 + lane) * 8];
                A2[0][t] = __builtin_amdgcn_mfma_f32_16x16x32_f16(a5[0][s], b, A2[0][t], 0, 0, 0);
                A2[1][t] = __builtin_amdgcn_mfma_f32_16x16x32_f16(a5[1][s], b, A2[1][t], 0, 0, 0);
            }

        // ---- segment max over 8 rows & store (2 y per tile, 4 per pair) ----
#pragma unroll
        for (int u = 0; u < 2; ++u)
#pragma unroll
            for (int t = 0; t < 4; ++t) {
                float pm = fmaxf(fmaxf(A2[u][t][0], A2[u][t][1]),
                                 fmaxf(A2[u][t][2], A2[u][t][3]));
                pm = fmaxf(pm, __shfl_xor(pm, 16, 64));
                if ((q & 1) == 0) {
                    const int y = pr * 4 + u * 2 + (q >> 1);
                    out[(long)y * 64 + t * 16 + n0] = pm;
                }
            }
    }
}

extern "C" void kernel_launch(void* const* d_in, const int* in_sizes, int n_in,
                              void* d_out, int out_size, void* d_ws, size_t ws_size,
                              hipStream_t stream) {
    (void)in_sizes; (void)n_in; (void)ws_size; (void)out_size;
    hipMemsetAsync(d_ws, 0, 64, stream);   // zero the dynamic-work counter
    pointnet_fused<<<512, 512, 0, stream>>>(
        (const float*)d_in[0],   // x
        (const float*)d_in[1],   // pos_x
        (const float*)d_in[2],   // pos_y
        (const int*)  d_in[3],   // x_idx
        (const float*)d_in[5],  (const float*)d_in[6],   // W0a, b0a
        (const float*)d_in[7],  (const float*)d_in[8],   // W1a, b1a
        (const float*)d_in[9],                            // Wsa
        (const float*)d_in[10], (const float*)d_in[11],  // W0b, b0b
        (const float*)d_in[12], (const float*)d_in[13],  // W1b, b1b
        (float*)d_out,
        (int*)d_ws);
}

// Round 6
// 126.066 us; speedup vs baseline: 2.3105x; 2.2859x over previous
//
#include <hip/hip_runtime.h>

// PointNetKnnInterpolator on MI355X (gfx950).
// h = [x[x_idx], pos_x[x_idx]-pos_y[y_idx]]  (400000 x 67)
// net = relu(h)@W0a+b0a ; dx = relu(net)@W1a+b1a ; h2 = h@Wsa + dx
// net2 = relu(h2)@W0b+b0b ; h3 = h2 + relu(net2)@W1b+b1b
// out[y] = max over 8 consecutive rows of h3.
//
// R6: R5 minus the dynamic atomic queue. R4/R5 both ran ~210 us because every
// wave-iteration gated on a same-cacheline device atomicAdd (12500 ops x ~40cyc
// device-wide serialization = ~208 us; MfmaUtil dilution 13.7->3.6 matches the
// 54->210 stretch exactly). Static stride assignment restores R3's scheduling
// while keeping the (finally clean) M=32 pairing:
//   - two 16-row tiles share every B-frag ds_read_b128 (LDS/tile 61->36 KB)
//   - 2x independent MFMA chains per wave (ILP on the latency chain)
//   - register discipline: mm3 first on raw hn, relu in place, mm5 into A2,
//     biases in LDS (R5: VGPR=52, no spills)
// Block=512 shares one 48 KB bfrag; LDS ~68 KB -> 2 blocks/CU = 16 waves/CU.

typedef _Float16 f16x8 __attribute__((ext_vector_type(8)));
typedef float    f32x4 __attribute__((ext_vector_type(4)));

constexpr int NROWS   = 50000 * 8;   // NY * K
constexpr int NPAIRS  = NROWS / 32;  // 12500 (32 rows per wave-iteration)
constexpr int NFRAG   = 48;          // 12 W0a + 8 W1a + 12 Wsa + 8 W0b + 8 W1b
constexpr int TSTRIDE = 72;          // halves per row of transition buffer
constexpr int BW      = 8;           // waves per block (block = 512)

// write relu(acc[4]+bias[4]) in C-layout to tbuf, read back two A-fragments.
// Leading fence orders any previous reads of tbuf before overwrite.
static __device__ __forceinline__ void xpose_relu(const f32x4* acc, const float* bb,
                                                  _Float16* tbuf, int q, int n0,
                                                  f16x8* af) {
    __threadfence_block();
#pragma unroll
    for (int t = 0; t < 4; ++t)
#pragma unroll
        for (int r = 0; r < 4; ++r) {
            float v = acc[t][r] + bb[t];
            tbuf[(q * 4 + r) * TSTRIDE + t * 16 + n0] = (_Float16)(v > 0.0f ? v : 0.0f);
        }
    __threadfence_block();
#pragma unroll
    for (int s = 0; s < 2; ++s)
        af[s] = *(const f16x8*)&tbuf[n0 * TSTRIDE + s * 32 + q * 8];
}

__global__ __launch_bounds__(512, 4)
void pointnet_fused(const float* __restrict__ x,
                    const float* __restrict__ pos_x,
                    const float* __restrict__ pos_y,
                    const int*   __restrict__ x_idx,
                    const float* __restrict__ W0a, const float* __restrict__ b0a,
                    const float* __restrict__ W1a, const float* __restrict__ b1a,
                    const float* __restrict__ Wsa,
                    const float* __restrict__ W0b, const float* __restrict__ b0b,
                    const float* __restrict__ W1b, const float* __restrict__ b1b,
                    float* __restrict__ out)
{
    __shared__ __align__(16) _Float16 bfrag[NFRAG * 64 * 8];       // 48 KiB
    __shared__ __align__(16) _Float16 trans[BW][16 * TSTRIDE];     // 18 KiB
    __shared__ float bias_lds[4 * 64];                             // 1 KiB

    const int tid = threadIdx.x;

    // ---- expand weights into B-fragment order (once per block) ----
    for (int p = tid; p < NFRAG * 64; p += 512) {
        const int f = p >> 6;
        const int l = p & 63;
        const float* W; int krows, fl;
        if (f < 12)      { W = W0a; krows = 67; fl = f; }
        else if (f < 20) { W = W1a; krows = 64; fl = f - 12; }
        else if (f < 32) { W = Wsa; krows = 67; fl = f - 20; }
        else if (f < 40) { W = W0b; krows = 64; fl = f - 32; }
        else             { W = W1b; krows = 64; fl = f - 40; }
        const int s = fl >> 2, t = fl & 3;
        const int n = t * 16 + (l & 15);
        const int kbase = s * 32 + (l >> 4) * 8;
        f16x8 v;
#pragma unroll
        for (int j = 0; j < 8; ++j) {
            const int k = kbase + j;
            v[j] = (_Float16)((k < krows) ? W[k * 64 + n] : 0.0f);
        }
        *(f16x8*)&bfrag[p * 8] = v;
    }
    if (tid < 256) {
        const int L = tid >> 6, i = tid & 63;
        const float* b = (L == 0) ? b0a : (L == 1) ? b1a : (L == 2) ? b0b : b1b;
        bias_lds[tid] = b[i];
    }
    __syncthreads();

    const int lane = tid & 63;
    const int wv   = tid >> 6;
    const int n0   = lane & 15;   // C col / A row m
    const int q    = lane >> 4;   // quad

    _Float16* tbuf = trans[wv];
    const int gwave  = blockIdx.x * BW + wv;
    const int nwaves = gridDim.x * BW;

    for (int pr = gwave; pr < NPAIRS; pr += nwaves) {
        // ---- gather A-side: h for both 16-row tiles (K padded 67->96) ----
        f16x8 hn[2][3];
#pragma unroll
        for (int u = 0; u < 2; ++u) {
            const int row = pr * 32 + u * 16 + n0;
            const int xi  = x_idx[row];
            const float* xp = x + (long)xi * 64;
#pragma unroll
            for (int s = 0; s < 2; ++s) {
                const float4* src = (const float4*)(xp + s * 32 + q * 8);
                float4 v0 = src[0], v1 = src[1];
                float vals[8] = {v0.x, v0.y, v0.z, v0.w, v1.x, v1.y, v1.z, v1.w};
#pragma unroll
                for (int j = 0; j < 8; ++j)
                    hn[u][s][j] = (_Float16)vals[j];
            }
            f16x8 z = {};
            hn[u][2] = z;
            if (q == 0) {
                const int yi = row >> 3;
#pragma unroll
                for (int j = 0; j < 3; ++j)
                    hn[u][2][j] = (_Float16)(pos_x[xi * 3 + j] - pos_y[yi * 3 + j]);
            }
        }

        // ---- mm3 FIRST: A2 = h @ Wsa  (raw hn; frags 20..31) ----
        f32x4 A2[2][4];
#pragma unroll
        for (int u = 0; u < 2; ++u)
#pragma unroll
            for (int t = 0; t < 4; ++t)
                A2[u][t] = (f32x4){0.f, 0.f, 0.f, 0.f};
#pragma unroll
        for (int s = 0; s < 3; ++s)
#pragma unroll
            for (int t = 0; t < 4; ++t) {
                f16x8 b = *(const f16x8*)&bfrag[((20 + s * 4 + t) * 64 + lane) * 8];
                A2[0][t] = __builtin_amdgcn_mfma_f32_16x16x32_f16(hn[0][s], b, A2[0][t], 0, 0, 0);
                A2[1][t] = __builtin_amdgcn_mfma_f32_16x16x32_f16(hn[1][s], b, A2[1][t], 0, 0, 0);
            }

        // ---- relu hn IN PLACE, then mm1: A1 = relu(h) @ W0a (frags 0..11) ----
#pragma unroll
        for (int u = 0; u < 2; ++u)
#pragma unroll
            for (int s = 0; s < 3; ++s)
#pragma unroll
                for (int j = 0; j < 8; ++j) {
                    _Float16 v = hn[u][s][j];
                    hn[u][s][j] = v > (_Float16)0 ? v : (_Float16)0;
                }

        f32x4 A1[2][4];
#pragma unroll
        for (int u = 0; u < 2; ++u)
#pragma unroll
            for (int t = 0; t < 4; ++t)
                A1[u][t] = (f32x4){0.f, 0.f, 0.f, 0.f};
#pragma unroll
        for (int s = 0; s < 3; ++s)
#pragma unroll
            for (int t = 0; t < 4; ++t) {
                f16x8 b = *(const f16x8*)&bfrag[((s * 4 + t) * 64 + lane) * 8];
                A1[0][t] = __builtin_amdgcn_mfma_f32_16x16x32_f16(hn[0][s], b, A1[0][t], 0, 0, 0);
                A1[1][t] = __builtin_amdgcn_mfma_f32_16x16x32_f16(hn[1][s], b, A1[1][t], 0, 0, 0);
            }

        // ---- transpose relu(A1 + b0a) -> a2 frags; mm2: A2 += a2 @ W1a ----
        float bb[4];
#pragma unroll
        for (int t = 0; t < 4; ++t) bb[t] = bias_lds[0 * 64 + t * 16 + n0];
        f16x8 a2[2][2];
        xpose_relu(A1[0], bb, tbuf, q, n0, a2[0]);
        xpose_relu(A1[1], bb, tbuf, q, n0, a2[1]);
#pragma unroll
        for (int s = 0; s < 2; ++s)
#pragma unroll
            for (int t = 0; t < 4; ++t) {
                f16x8 b = *(const f16x8*)&bfrag[((12 + s * 4 + t) * 64 + lane) * 8];
                A2[0][t] = __builtin_amdgcn_mfma_f32_16x16x32_f16(a2[0][s], b, A2[0][t], 0, 0, 0);
                A2[1][t] = __builtin_amdgcn_mfma_f32_16x16x32_f16(a2[1][s], b, A2[1][t], 0, 0, 0);
            }

        // ---- A2 += b1a (h2 complete); transpose relu(A2) -> a4 ----
#pragma unroll
        for (int t = 0; t < 4; ++t) bb[t] = bias_lds[1 * 64 + t * 16 + n0];
#pragma unroll
        for (int u = 0; u < 2; ++u)
#pragma unroll
            for (int t = 0; t < 4; ++t)
#pragma unroll
                for (int r = 0; r < 4; ++r)
                    A2[u][t][r] += bb[t];
        const float bz[4] = {0.f, 0.f, 0.f, 0.f};
        f16x8 a4[2][2];
        xpose_relu(A2[0], bz, tbuf, q, n0, a4[0]);
        xpose_relu(A2[1], bz, tbuf, q, n0, a4[1]);

        // ---- mm4: A3 = a4 @ W0b (frags 32..39) ----
        f32x4 A3[2][4];
#pragma unroll
        for (int u = 0; u < 2; ++u)
#pragma unroll
            for (int t = 0; t < 4; ++t)
                A3[u][t] = (f32x4){0.f, 0.f, 0.f, 0.f};
#pragma unroll
        for (int s = 0; s < 2; ++s)
#pragma unroll
            for (int t = 0; t < 4; ++t) {
                f16x8 b = *(const f16x8*)&bfrag[((32 + s * 4 + t) * 64 + lane) * 8];
                A3[0][t] = __builtin_amdgcn_mfma_f32_16x16x32_f16(a4[0][s], b, A3[0][t], 0, 0, 0);
                A3[1][t] = __builtin_amdgcn_mfma_f32_16x16x32_f16(a4[1][s], b, A3[1][t], 0, 0, 0);
            }

        // ---- transpose relu(A3 + b0b) -> a5; mm5: A2 += b1b + a5 @ W1b ----
#pragma unroll
        for (int t = 0; t < 4; ++t) bb[t] = bias_lds[2 * 64 + t * 16 + n0];
        f16x8 a5[2][2];
        xpose_relu(A3[0], bb, tbuf, q, n0, a5[0]);
        xpose_relu(A3[1], bb, tbuf, q, n0, a5[1]);

#pragma unroll
        for (int t = 0; t < 4; ++t) bb[t] = bias_lds[3 * 64 + t * 16 + n0];
#pragma unroll
        for (int u = 0; u < 2; ++u)
#pragma unroll
            for (int t = 0; t < 4; ++t)
#pragma unroll
                for (int r = 0; r < 4; ++r)
                    A2[u][t][r] += bb[t];
#pragma unroll
        for (int s = 0; s < 2; ++s)
#pragma unroll
            for (int t = 0; t < 4; ++t) {
                f16x8 b = *(const f16x8*)&bfrag[((40 + s * 4 + t) * 64 + lane) * 8];
                A2[0][t] = __builtin_amdgcn_mfma_f32_16x16x32_f16(a5[0][s], b, A2[0][t], 0, 0, 0);
                A2[1][t] = __builtin_amdgcn_mfma_f32_16x16x32_f16(a5[1][s], b, A2[1][t], 0, 0, 0);
            }

        // ---- segment max over 8 rows & store (2 y per tile, 4 per pair) ----
#pragma unroll
        for (int u = 0; u < 2; ++u)
#pragma unroll
            for (int t = 0; t < 4; ++t) {
                float pm = fmaxf(fmaxf(A2[u][t][0], A2[u][t][1]),
                                 fmaxf(A2[u][t][2], A2[u][t][3]));
                pm = fmaxf(pm, __shfl_xor(pm, 16, 64));
                if ((q & 1) == 0) {
                    const int y = pr * 4 + u * 2 + (q >> 1);
                    out[(long)y * 64 + t * 16 + n0] = pm;
                }
            }
    }
}

extern "C" void kernel_launch(void* const* d_in, const int* in_sizes, int n_in,
                              void* d_out, int out_size, void* d_ws, size_t ws_size,
                              hipStream_t stream) {
    (void)in_sizes; (void)n_in; (void)d_ws; (void)ws_size; (void)out_size;
    pointnet_fused<<<512, 512, 0, stream>>>(
        (const float*)d_in[0],   // x
        (const float*)d_in[1],   // pos_x
        (const float*)d_in[2],   // pos_y
        (const int*)  d_in[3],   // x_idx
        (const float*)d_in[5],  (const float*)d_in[6],   // W0a, b0a
        (const float*)d_in[7],  (const float*)d_in[8],   // W1a, b1a
        (const float*)d_in[9],                            // Wsa
        (const float*)d_in[10], (const float*)d_in[11],  // W0b, b0b
        (const float*)d_in[12], (const float*)d_in[13],  // W1b, b1b
        (float*)d_out);
}